// Round 5
// baseline (671.174 us; speedup 1.0000x reference)
//
#include <hip/hip_runtime.h>

#define SEQ   1024
#define BATCH 8
#define DIM   512
#define NTOK  (SEQ * BATCH)

typedef unsigned short ushort_t;
typedef unsigned int uint_t;
typedef __attribute__((ext_vector_type(8))) short s16x8;
typedef __attribute__((ext_vector_type(4))) float f32x4;

union F4 { float4 v; float f[4]; };

__device__ __forceinline__ float sigmoid_f(float x) { return 1.0f / (1.0f + expf(-x)); }
__device__ __forceinline__ float silu_f(float x)    { return x * sigmoid_f(x); }

__device__ __forceinline__ ushort_t f2bf(float x) {
  uint_t u = __float_as_uint(x);
  return (ushort_t)((u + 0x7FFFu + ((u >> 16) & 1u)) >> 16);
}
__device__ __forceinline__ float bf2f(ushort_t h) {
  return __uint_as_float(((uint_t)h) << 16);
}

__device__ __forceinline__ void gload16(const void* g, void* l) {
  __builtin_amdgcn_global_load_lds(
      (const __attribute__((address_space(1))) void*)g,
      (__attribute__((address_space(3))) void*)l,
      16, 0, 0);
}

// ---------------------------------------------------------------------------
// Fused f32 -> bf16 cast over 8 segments (one launch for all weight casts).
// ---------------------------------------------------------------------------
struct CastArgs {
  const float* src[8];
  ushort_t*    dst[8];
  int          cum8[8];   // start (in 8-elem units) of each segment
};

__global__ __launch_bounds__(256) void f2b_multi(CastArgs a, int total8)
{
  const int i = blockIdx.x * 256 + threadIdx.x;
  if (i >= total8) return;
  int s = 0;
  #pragma unroll
  for (int k = 1; k < 8; ++k) s += (i >= a.cum8[k]) ? 1 : 0;
  const int j = i - a.cum8[s];
  const float* src = a.src[s] + (size_t)j * 8;
  F4 x0, x1;
  x0.v = *(const float4*)(src);
  x1.v = *(const float4*)(src + 4);
  uint4 o;
  o.x = (uint_t)f2bf(x0.f[0]) | ((uint_t)f2bf(x0.f[1]) << 16);
  o.y = (uint_t)f2bf(x0.f[2]) | ((uint_t)f2bf(x0.f[3]) << 16);
  o.z = (uint_t)f2bf(x1.f[0]) | ((uint_t)f2bf(x1.f[1]) << 16);
  o.w = (uint_t)f2bf(x1.f[2]) | ((uint_t)f2bf(x1.f[3]) << 16);
  *(uint4*)(a.dst[s] + (size_t)j * 8) = o;
}

// ---------------------------------------------------------------------------
// LayerNorm (512). One wave per row, 4 rows/block, no cross-wave sync.
// BF=1: bf16 out, BF=0: fp32 out.
// ---------------------------------------------------------------------------
template <int BF>
__global__ __launch_bounds__(256) void ln512_kernel(
    const float* __restrict__ in, const float* __restrict__ g,
    const float* __restrict__ b, void* __restrict__ outv)
{
  const int row = blockIdx.x * 4 + (threadIdx.x >> 6);
  const int l   = threadIdx.x & 63;
  const float* rp = in + (size_t)row * DIM + l * 8;
  F4 v0, v1;
  v0.v = *(const float4*)(rp);
  v1.v = *(const float4*)(rp + 4);
  float sum = 0.f, sq = 0.f;
  #pragma unroll
  for (int j = 0; j < 4; ++j) { sum += v0.f[j] + v1.f[j];
                                sq  += v0.f[j]*v0.f[j] + v1.f[j]*v1.f[j]; }
  #pragma unroll
  for (int m = 32; m >= 1; m >>= 1) {
    sum += __shfl_xor(sum, m, 64);
    sq  += __shfl_xor(sq,  m, 64);
  }
  const float mu   = sum * (1.0f / DIM);
  const float var  = sq * (1.0f / DIM) - mu * mu;
  const float rinv = rsqrtf(var + 1e-5f);
  F4 g0, g1, b0, b1;
  g0.v = *(const float4*)(g + l * 8);     g1.v = *(const float4*)(g + l * 8 + 4);
  b0.v = *(const float4*)(b + l * 8);     b1.v = *(const float4*)(b + l * 8 + 4);
  float o[8];
  #pragma unroll
  for (int j = 0; j < 4; ++j) {
    o[j]     = (v0.f[j] - mu) * rinv * g0.f[j] + b0.f[j];
    o[4 + j] = (v1.f[j] - mu) * rinv * g1.f[j] + b1.f[j];
  }
  if (BF) {
    uint4 u;
    u.x = (uint_t)f2bf(o[0]) | ((uint_t)f2bf(o[1]) << 16);
    u.y = (uint_t)f2bf(o[2]) | ((uint_t)f2bf(o[3]) << 16);
    u.z = (uint_t)f2bf(o[4]) | ((uint_t)f2bf(o[5]) << 16);
    u.w = (uint_t)f2bf(o[6]) | ((uint_t)f2bf(o[7]) << 16);
    *(uint4*)((ushort_t*)outv + (size_t)row * DIM + l * 8) = u;
  } else {
    F4 w0, w1;
    #pragma unroll
    for (int j = 0; j < 4; ++j) { w0.f[j] = o[j]; w1.f[j] = o[4 + j]; }
    *(float4*)((float*)outv + (size_t)row * DIM + l * 8)     = w0.v;
    *(float4*)((float*)outv + (size_t)row * DIM + l * 8 + 4) = w1.v;
  }
}

// ---------------------------------------------------------------------------
// bf16 NT GEMM: out[M,N] = A*W^T + bias. EPI0: fp32 out. EPI1: fp32 out with
// residual (res + alpha*(acc+bias)).
// ---------------------------------------------------------------------------
template <int EPI>
__global__ __launch_bounds__(256) void gemm_bf16(
    const ushort_t* __restrict__ A, const ushort_t* __restrict__ W,
    const float* __restrict__ bias, float* __restrict__ out,
    int N, int K, const float* __restrict__ res, float alpha)
{
  __shared__ ushort_t As[128 * 32];
  __shared__ ushort_t Ws[128 * 32];
  const int t    = threadIdx.x;
  const int lane = t & 63;
  const int w    = t >> 6;
  const int wm   = w >> 1, wn = w & 1;
  const int m0   = blockIdx.y << 7, n0 = blockIdx.x << 7;

  f32x4 acc[4][4] = {};

  const int lds0 = __builtin_amdgcn_readfirstlane((w * 64) * 16);
  const int lds1 = __builtin_amdgcn_readfirstlane((256 + w * 64) * 16);
  const int r0c  = t >> 2;
  const int r1c  = 64 + (t >> 2);
  const int cc   = (t & 3) << 3;

  for (int k0 = 0; k0 < K; k0 += 32) {
    gload16(A + (size_t)(m0 + r0c) * K + k0 + cc, (char*)As + lds0);
    gload16(A + (size_t)(m0 + r1c) * K + k0 + cc, (char*)As + lds1);
    gload16(W + (size_t)(n0 + r0c) * K + k0 + cc, (char*)Ws + lds0);
    gload16(W + (size_t)(n0 + r1c) * K + k0 + cc, (char*)Ws + lds1);
    __syncthreads();
    s16x8 a[4], b[4];
    #pragma unroll
    for (int i = 0; i < 4; ++i)
      a[i] = *(const s16x8*)&As[(wm * 64 + i * 16 + (lane & 15)) * 32 + ((lane >> 4) << 3)];
    #pragma unroll
    for (int j = 0; j < 4; ++j)
      b[j] = *(const s16x8*)&Ws[(wn * 64 + j * 16 + (lane & 15)) * 32 + ((lane >> 4) << 3)];
    #pragma unroll
    for (int i = 0; i < 4; ++i)
      #pragma unroll
      for (int j = 0; j < 4; ++j)
        acc[i][j] = __builtin_amdgcn_mfma_f32_16x16x32_bf16(a[i], b[j], acc[i][j], 0, 0, 0);
    __syncthreads();
  }

  #pragma unroll
  for (int i = 0; i < 4; ++i) {
    #pragma unroll
    for (int j = 0; j < 4; ++j) {
      const int col  = n0 + wn * 64 + j * 16 + (lane & 15);
      const int rowb = m0 + wm * 64 + i * 16 + ((lane >> 4) << 2);
      const float bc = bias[col];
      #pragma unroll
      for (int r = 0; r < 4; ++r) {
        const size_t idx = (size_t)(rowb + r) * N + col;
        float v = acc[i][j][r] + bc;
        if (EPI == 1) v = res[idx] + alpha * v;
        out[idx] = v;
      }
    }
  }
}

// ---------------------------------------------------------------------------
// QKV GEMM: bf16 out. Q,K cols (<1024) -> qkvb[tok][1536]; V cols -> Vt
// transposed: Vt[(b*8+h)*64 + d][s] (bf16).
// ---------------------------------------------------------------------------
__global__ __launch_bounds__(256) void gemm_qkv_bf16(
    const ushort_t* __restrict__ A, const ushort_t* __restrict__ W,
    const float* __restrict__ bias, ushort_t* __restrict__ qkvb,
    ushort_t* __restrict__ Vt, int K)
{
  const int N = 1536;
  __shared__ ushort_t As[128 * 32];
  __shared__ ushort_t Ws[128 * 32];
  const int t    = threadIdx.x;
  const int lane = t & 63;
  const int w    = t >> 6;
  const int wm   = w >> 1, wn = w & 1;
  const int m0   = blockIdx.y << 7, n0 = blockIdx.x << 7;

  f32x4 acc[4][4] = {};

  const int lds0 = __builtin_amdgcn_readfirstlane((w * 64) * 16);
  const int lds1 = __builtin_amdgcn_readfirstlane((256 + w * 64) * 16);
  const int r0c  = t >> 2;
  const int r1c  = 64 + (t >> 2);
  const int cc   = (t & 3) << 3;

  for (int k0 = 0; k0 < K; k0 += 32) {
    gload16(A + (size_t)(m0 + r0c) * K + k0 + cc, (char*)As + lds0);
    gload16(A + (size_t)(m0 + r1c) * K + k0 + cc, (char*)As + lds1);
    gload16(W + (size_t)(n0 + r0c) * K + k0 + cc, (char*)Ws + lds0);
    gload16(W + (size_t)(n0 + r1c) * K + k0 + cc, (char*)Ws + lds1);
    __syncthreads();
    s16x8 a[4], b[4];
    #pragma unroll
    for (int i = 0; i < 4; ++i)
      a[i] = *(const s16x8*)&As[(wm * 64 + i * 16 + (lane & 15)) * 32 + ((lane >> 4) << 3)];
    #pragma unroll
    for (int j = 0; j < 4; ++j)
      b[j] = *(const s16x8*)&Ws[(wn * 64 + j * 16 + (lane & 15)) * 32 + ((lane >> 4) << 3)];
    #pragma unroll
    for (int i = 0; i < 4; ++i)
      #pragma unroll
      for (int j = 0; j < 4; ++j)
        acc[i][j] = __builtin_amdgcn_mfma_f32_16x16x32_bf16(a[i], b[j], acc[i][j], 0, 0, 0);
    __syncthreads();
  }

  #pragma unroll
  for (int i = 0; i < 4; ++i) {
    #pragma unroll
    for (int j = 0; j < 4; ++j) {
      const int col  = n0 + wn * 64 + j * 16 + (lane & 15);
      const int rowb = m0 + wm * 64 + i * 16 + ((lane >> 4) << 2);
      const float bc = bias[col];
      if (col < 1024) {
        #pragma unroll
        for (int r = 0; r < 4; ++r)
          qkvb[(size_t)(rowb + r) * N + col] = f2bf(acc[i][j][r] + bc);
      } else {
        const int vc = col - 1024;
        const int hh = vc >> 6, d = vc & 63;
        const int bb = rowb >> 10, s = rowb & 1023;
        ushort4 o;
        o.x = f2bf(acc[i][j][0] + bc);
        o.y = f2bf(acc[i][j][1] + bc);
        o.z = f2bf(acc[i][j][2] + bc);
        o.w = f2bf(acc[i][j][3] + bc);
        *(ushort4*)&Vt[(size_t)((bb * 8 + hh) * 64 + d) * 1024 + s] = o;
      }
    }
  }
}

// ---------------------------------------------------------------------------
// bf16 GLU GEMM. CGLU=0: silu(a)*c (FF); CGLU=1: a*sigmoid(c) (conv).
// ---------------------------------------------------------------------------
template <int CGLU>
__global__ __launch_bounds__(256) void gemm_glu_bf16(
    const ushort_t* __restrict__ A, const ushort_t* __restrict__ W,
    const float* __restrict__ bias, ushort_t* __restrict__ out,
    int NG, int K)
{
  __shared__ ushort_t As[128 * 32];
  __shared__ ushort_t Was[64 * 32];
  __shared__ ushort_t Wcs[64 * 32];
  const int t    = threadIdx.x;
  const int lane = t & 63;
  const int w    = t >> 6;
  const int wm   = w >> 1, wn = w & 1;
  const int m0   = blockIdx.y << 7, n0 = blockIdx.x << 6;

  f32x4 acca[4][2] = {};
  f32x4 accc[4][2] = {};

  const int lds0 = __builtin_amdgcn_readfirstlane((w * 64) * 16);
  const int lds1 = __builtin_amdgcn_readfirstlane((256 + w * 64) * 16);
  const int r0c  = t >> 2;
  const int r1c  = 64 + (t >> 2);
  const int cc   = (t & 3) << 3;

  const ushort_t* Wc = W + (size_t)NG * K;

  for (int k0 = 0; k0 < K; k0 += 32) {
    gload16(A  + (size_t)(m0 + r0c) * K + k0 + cc, (char*)As  + lds0);
    gload16(A  + (size_t)(m0 + r1c) * K + k0 + cc, (char*)As  + lds1);
    gload16(W  + (size_t)(n0 + r0c) * K + k0 + cc, (char*)Was + lds0);
    gload16(Wc + (size_t)(n0 + r0c) * K + k0 + cc, (char*)Wcs + lds0);
    __syncthreads();
    s16x8 a[4], ba[2], bc[2];
    #pragma unroll
    for (int i = 0; i < 4; ++i)
      a[i] = *(const s16x8*)&As[(wm * 64 + i * 16 + (lane & 15)) * 32 + ((lane >> 4) << 3)];
    #pragma unroll
    for (int j = 0; j < 2; ++j) {
      const int roff = (wn * 32 + j * 16 + (lane & 15)) * 32 + ((lane >> 4) << 3);
      ba[j] = *(const s16x8*)&Was[roff];
      bc[j] = *(const s16x8*)&Wcs[roff];
    }
    #pragma unroll
    for (int i = 0; i < 4; ++i)
      #pragma unroll
      for (int j = 0; j < 2; ++j) {
        acca[i][j] = __builtin_amdgcn_mfma_f32_16x16x32_bf16(a[i], ba[j], acca[i][j], 0, 0, 0);
        accc[i][j] = __builtin_amdgcn_mfma_f32_16x16x32_bf16(a[i], bc[j], accc[i][j], 0, 0, 0);
      }
    __syncthreads();
  }

  #pragma unroll
  for (int i = 0; i < 4; ++i) {
    #pragma unroll
    for (int j = 0; j < 2; ++j) {
      const int col  = n0 + wn * 32 + j * 16 + (lane & 15);
      const int rowb = m0 + wm * 64 + i * 16 + ((lane >> 4) << 2);
      const float b1 = bias[col];
      const float b2 = bias[NG + col];
      #pragma unroll
      for (int r = 0; r < 4; ++r) {
        const float av = acca[i][j][r] + b1;
        const float cv = accc[i][j][r] + b2;
        const float o  = CGLU ? (av * sigmoid_f(cv)) : (silu_f(av) * cv);
        out[(size_t)(rowb + r) * NG + col] = f2bf(o);
      }
    }
  }
}

// ---------------------------------------------------------------------------
// MFMA flash attention (bf16 inputs, fp32 softmax/acc).
// ---------------------------------------------------------------------------
__global__ __launch_bounds__(256) void attn_mfma(
    const ushort_t* __restrict__ qkv, const ushort_t* __restrict__ Vt,
    ushort_t* __restrict__ out)
{
  __shared__ ushort_t Ks[64 * 64];
  __shared__ ushort_t Vs[64 * 64];
  __shared__ ushort_t Ps[4][16 * 64];

  const int t    = threadIdx.x;
  const int lane = t & 63;
  const int w    = t >> 6;
  const int i    = lane & 15;
  const int g    = lane >> 4;
  const int bh   = blockIdx.x;
  const int b    = bh >> 3, h = bh & 7;
  const int qt   = blockIdx.y;

  s16x8 qf[2];
  {
    const ushort_t* qrow = qkv + (size_t)(b * SEQ + qt * 64 + w * 16 + i) * 1536 + h * 64;
    qf[0] = *(const s16x8*)(qrow + g * 8);
    qf[1] = *(const s16x8*)(qrow + 32 + g * 8);
  }

  float m_[4], l_[4];
  f32x4 po[4] = {};
  #pragma unroll
  for (int r = 0; r < 4; ++r) { m_[r] = -1e30f; l_[r] = 0.0f; }

  const int e0   = w * 2;
  const int off0 = __builtin_amdgcn_readfirstlane(e0 * 1024);
  const int off1 = __builtin_amdgcn_readfirstlane(e0 * 1024 + 1024);

  for (int kvt = 0; kvt < 16; ++kvt) {
    __syncthreads();
    {
      const int s_a = e0 * 64 + lane;
      const int ra = s_a >> 3, ca = (s_a & 7) ^ (ra & 7);
      const int s_b = s_a + 64;
      const int rb = s_b >> 3, cb2 = (s_b & 7) ^ (rb & 7);
      gload16(qkv + (size_t)(b * SEQ + kvt * 64 + ra) * 1536 + 512 + h * 64 + ca * 8,
              (char*)Ks + off0);
      gload16(qkv + (size_t)(b * SEQ + kvt * 64 + rb) * 1536 + 512 + h * 64 + cb2 * 8,
              (char*)Ks + off1);
      gload16(Vt + (size_t)(bh * 64 + ra) * SEQ + kvt * 64 + ca * 8,
              (char*)Vs + off0);
      gload16(Vt + (size_t)(bh * 64 + rb) * SEQ + kvt * 64 + cb2 * 8,
              (char*)Vs + off1);
    }
    __syncthreads();

    f32x4 sc[4] = {};
    #pragma unroll
    for (int jj = 0; jj < 4; ++jj) {
      const int row = jj * 16 + i;
      #pragma unroll
      for (int dd = 0; dd < 2; ++dd) {
        const int byteoff = row * 128 + ((dd * 64 + g * 16) ^ ((row & 7) << 4));
        const s16x8 kf = *(const s16x8*)((const char*)Ks + byteoff);
        sc[jj] = __builtin_amdgcn_mfma_f32_16x16x32_bf16(qf[dd], kf, sc[jj], 0, 0, 0);
      }
    }

    #pragma unroll
    for (int r = 0; r < 4; ++r) {
      float v0 = sc[0][r] * 0.125f, v1 = sc[1][r] * 0.125f;
      float v2 = sc[2][r] * 0.125f, v3 = sc[3][r] * 0.125f;
      float mx = fmaxf(fmaxf(v0, v1), fmaxf(v2, v3));
      mx = fmaxf(mx, __shfl_xor(mx, 1));
      mx = fmaxf(mx, __shfl_xor(mx, 2));
      mx = fmaxf(mx, __shfl_xor(mx, 4));
      mx = fmaxf(mx, __shfl_xor(mx, 8));
      const float mn = fmaxf(m_[r], mx);
      const float al = __expf(m_[r] - mn);
      const float p0 = __expf(v0 - mn), p1 = __expf(v1 - mn);
      const float p2 = __expf(v2 - mn), p3 = __expf(v3 - mn);
      float rs = p0 + p1 + p2 + p3;
      rs += __shfl_xor(rs, 1); rs += __shfl_xor(rs, 2);
      rs += __shfl_xor(rs, 4); rs += __shfl_xor(rs, 8);
      l_[r] = l_[r] * al + rs;
      m_[r] = mn;
      #pragma unroll
      for (int dt = 0; dt < 4; ++dt) po[dt][r] *= al;
      const int q = 4 * g + r;
      const int key = (q & 7) << 4;
      ushort_t* pb = &Ps[w][0];
      ((ushort_t*)((char*)pb + q * 128 + ((2 * i) ^ key)))[0]       = f2bf(p0);
      ((ushort_t*)((char*)pb + q * 128 + ((32 + 2 * i) ^ key)))[0]  = f2bf(p1);
      ((ushort_t*)((char*)pb + q * 128 + ((64 + 2 * i) ^ key)))[0]  = f2bf(p2);
      ((ushort_t*)((char*)pb + q * 128 + ((96 + 2 * i) ^ key)))[0]  = f2bf(p3);
    }

    #pragma unroll
    for (int kc = 0; kc < 2; ++kc) {
      const int pbyte = i * 128 + ((kc * 64 + g * 16) ^ ((i & 7) << 4));
      const s16x8 pf = *(const s16x8*)((const char*)&Ps[w][0] + pbyte);
      #pragma unroll
      for (int dt = 0; dt < 4; ++dt) {
        const int vrow = dt * 16 + i;
        const int vbyte = vrow * 128 + ((kc * 64 + g * 16) ^ ((vrow & 7) << 4));
        const s16x8 vf = *(const s16x8*)((const char*)Vs + vbyte);
        po[dt] = __builtin_amdgcn_mfma_f32_16x16x32_bf16(pf, vf, po[dt], 0, 0, 0);
      }
    }
  }

  #pragma unroll
  for (int r = 0; r < 4; ++r) {
    const float inv = 1.0f / l_[r];
    const size_t row = (size_t)(b * SEQ + qt * 64 + w * 16 + 4 * g + r);
    #pragma unroll
    for (int dt = 0; dt < 4; ++dt)
      out[row * 512 + h * 64 + dt * 16 + i] = f2bf(po[dt][r] * inv);
  }
}

// ---------------------------------------------------------------------------
// Grouped conv1d (K=31) + bias + BN + SiLU. bf16 in/out, fp32 internal.
// lane = s-position -> channel indices wave-uniform -> SGPR weight loads.
// ---------------------------------------------------------------------------
__global__ __launch_bounds__(256) void dwconv_kernel(
    const ushort_t* __restrict__ in, const float* __restrict__ w,
    const float* __restrict__ dwb, const float* __restrict__ bng,
    const float* __restrict__ bnb, const float* __restrict__ bnm,
    const float* __restrict__ bnv, ushort_t* __restrict__ out)
{
  __shared__ float tile[94][65];   // [s0-15 .. s0+78][64 ch], pad 65: 2-way free
  const int s0 = blockIdx.x << 6;
  const int c0 = blockIdx.y << 6;
  const int b  = blockIdx.z;
  const int t  = threadIdx.x;

  // ---- stage input (bf16 -> f32) ----
  {
    const int cl4 = (t & 15) << 2;
    #pragma unroll
    for (int it = 0; it < 6; ++it) {
      const int rr = it * 16 + (t >> 4);
      if (rr < 94) {
        const int gs = s0 - 15 + rr;
        float4 fv = make_float4(0.f, 0.f, 0.f, 0.f);
        if (gs >= 0 && gs < SEQ) {
          ushort4 uv = *(const ushort4*)(in + (size_t)(b * SEQ + gs) * 1024 + c0 + cl4);
          fv = make_float4(bf2f(uv.x), bf2f(uv.y), bf2f(uv.z), bf2f(uv.w));
        }
        tile[rr][cl4 + 0] = fv.x;
        tile[rr][cl4 + 1] = fv.y;
        tile[rr][cl4 + 2] = fv.z;
        tile[rr][cl4 + 3] = fv.w;
      }
    }
  }
  __syncthreads();

  const int wv   = t >> 6;   // wave 0..3 -> 16 channels
  const int lane = t & 63;   // s offset within tile

  float res[16];
  #pragma unroll
  for (int grp = 0; grp < 2; ++grp) {
    const int chb = wv * 16 + grp * 8;                                   // local ch base
    const int gcb = __builtin_amdgcn_readfirstlane(c0 + chb);            // uniform
    const float* wbase = w + (size_t)gcb * 248;                          // [8co][8ci][31]
    float acc[8] = {};
    for (int ci = 0; ci < 8; ++ci) {
      float win[31];
      #pragma unroll
      for (int r = 0; r < 31; ++r) win[r] = tile[lane + r][chb + ci];
      const float* wp = wbase + ci * 31;
      #pragma unroll
      for (int co = 0; co < 8; ++co) {
        #pragma unroll
        for (int tap = 0; tap < 31; ++tap)
          acc[co] = fmaf(wp[co * 248 + tap], win[tap], acc[co]);
      }
    }
    #pragma unroll
    for (int co = 0; co < 8; ++co) res[grp * 8 + co] = acc[co];
  }

  // ---- bias + BN + SiLU, transpose via LDS for coalesced writes ----
  __syncthreads();
  #pragma unroll
  for (int grp = 0; grp < 2; ++grp) {
    const int chb = wv * 16 + grp * 8;
    const int gcb = __builtin_amdgcn_readfirstlane(c0 + chb);
    #pragma unroll
    for (int co = 0; co < 8; ++co) {
      const int gc = gcb + co;
      float y = res[grp * 8 + co] + dwb[gc];
      y = (y - bnm[gc]) * rsqrtf(bnv[gc] + 1e-5f) * bng[gc] + bnb[gc];
      tile[lane][chb + co] = silu_f(y);
    }
  }
  __syncthreads();
  {
    const int r  = t >> 2;           // s row 0..63
    const int cq = (t & 3) << 4;     // 16-ch block
    uint4 o1;
    uint_t p[8];
    #pragma unroll
    for (int j = 0; j < 8; ++j) {
      const float a = tile[r][cq + 2 * j];
      const float c = tile[r][cq + 2 * j + 1];
      p[j] = (uint_t)f2bf(a) | ((uint_t)f2bf(c) << 16);
    }
    ushort_t* dst = out + (size_t)(b * SEQ + s0 + r) * 1024 + c0 + cq;
    o1 = make_uint4(p[0], p[1], p[2], p[3]);
    *(uint4*)dst = o1;
    o1 = make_uint4(p[4], p[5], p[6], p[7]);
    *(uint4*)(dst + 8) = o1;
  }
}

// ---------------------------------------------------------------------------
extern "C" void kernel_launch(void* const* d_in, const int* in_sizes, int n_in,
                              void* d_out, int out_size, void* d_ws, size_t ws_size,
                              hipStream_t stream)
{
  (void)in_sizes; (void)n_in; (void)out_size; (void)ws_size;
  const float* x        = (const float*)d_in[0];
  const float* ff1_g    = (const float*)d_in[1];
  const float* ff1_b    = (const float*)d_in[2];
  const float* ff1_win  = (const float*)d_in[3];
  const float* ff1_bin  = (const float*)d_in[4];
  const float* ff1_wout = (const float*)d_in[5];
  const float* ff1_bout = (const float*)d_in[6];
  const float* attn_g   = (const float*)d_in[7];
  const float* attn_b   = (const float*)d_in[8];
  const float* wqkv     = (const float*)d_in[9];
  const float* bqkv     = (const float*)d_in[10];
  const float* wo       = (const float*)d_in[11];
  const float* bo       = (const float*)d_in[12];
  const float* conv_g   = (const float*)d_in[13];
  const float* conv_b   = (const float*)d_in[14];
  const float* pw1_w    = (const float*)d_in[15];
  const float* pw1_b    = (const float*)d_in[16];
  const float* dw_w     = (const float*)d_in[17];
  const float* dw_b     = (const float*)d_in[18];
  const float* bn_g     = (const float*)d_in[19];
  const float* bn_b     = (const float*)d_in[20];
  const float* bn_m     = (const float*)d_in[21];
  const float* bn_v     = (const float*)d_in[22];
  const float* pw2_w    = (const float*)d_in[23];
  const float* pw2_b    = (const float*)d_in[24];
  const float* ff2_g    = (const float*)d_in[25];
  const float* ff2_b    = (const float*)d_in[26];
  const float* ff2_win  = (const float*)d_in[27];
  const float* ff2_bin  = (const float*)d_in[28];
  const float* ff2_wout = (const float*)d_in[29];
  const float* ff2_bout = (const float*)d_in[30];
  const float* fn_g     = (const float*)d_in[31];
  const float* fn_b     = (const float*)d_in[32];

  // workspace layout (bytes)
  char* wsb = (char*)d_ws;
  float*    xc    = (float*)(wsb);                           // 16 MB fp32 residual
  ushort_t* qkvb  = (ushort_t*)(wsb + (size_t)(16 << 20));   // 24 MB bf16 qkv (Q,K)
  ushort_t* vtb   = (ushort_t*)(wsb + (size_t)(40 << 20));   //  8 MB bf16 V^T
  ushort_t* h_bf  = (ushort_t*)(wsb + (size_t)(48 << 20));   //  8 MB bf16 LN out
  ushort_t* g_bf  = (ushort_t*)(wsb + (size_t)(56 << 20));   // 32 MB bf16 GLU out
  ushort_t* tb_bf = (ushort_t*)(wsb + (size_t)(88 << 20));   //  8 MB bf16 attn out
  ushort_t* cv_bf = (ushort_t*)(wsb + (size_t)(96 << 20));   // 16 MB bf16 conv out
  ushort_t* wb    = (ushort_t*)(wsb + (size_t)(112 << 20));  // ~18 MB bf16 weights

  ushort_t* ff1win_b  = wb;
  ushort_t* ff1wout_b = ff1win_b + 4096 * 512;
  ushort_t* wqkv_b    = ff1wout_b + 512 * 2048;
  ushort_t* wo_b      = wqkv_b + 1536 * 512;
  ushort_t* pw1w_b    = wo_b + 512 * 512;
  ushort_t* pw2w_b    = pw1w_b + 2048 * 512;
  ushort_t* ff2win_b  = pw2w_b + 512 * 1024;
  ushort_t* ff2wout_b = ff2win_b + 4096 * 512;

  float* outp = (float*)d_out;
  const dim3 B256(256);

  // ---- fused weight casts (one launch) ----
  {
    CastArgs a;
    const float* srcs[8] = {ff1_win, ff1_wout, wqkv, wo, pw1_w, pw2_w, ff2_win, ff2_wout};
    ushort_t*    dsts[8] = {ff1win_b, ff1wout_b, wqkv_b, wo_b, pw1w_b, pw2w_b, ff2win_b, ff2wout_b};
    const int    ns[8]   = {4096*512, 512*2048, 1536*512, 512*512,
                            2048*512, 512*1024, 4096*512, 512*2048};
    int cum = 0;
    for (int i = 0; i < 8; ++i) {
      a.src[i] = srcs[i]; a.dst[i] = dsts[i]; a.cum8[i] = cum; cum += ns[i] / 8;
    }
    f2b_multi<<<dim3((cum + 255) / 256), B256, 0, stream>>>(a, cum);
  }

  // ---- FF1: xc = x + 0.5*ff(x) ----
  ln512_kernel<1><<<dim3(NTOK / 4), B256, 0, stream>>>(x, ff1_g, ff1_b, h_bf);
  gemm_glu_bf16<0><<<dim3(32, 64), B256, 0, stream>>>(h_bf, ff1win_b, ff1_bin, g_bf, 2048, 512);
  gemm_bf16<1><<<dim3(4, 64), B256, 0, stream>>>(g_bf, ff1wout_b, ff1_bout, xc, 512, 2048, x, 0.5f);

  // ---- Attention: xc += attn(xc) ----
  ln512_kernel<1><<<dim3(NTOK / 4), B256, 0, stream>>>(xc, attn_g, attn_b, h_bf);
  gemm_qkv_bf16<<<dim3(12, 64), B256, 0, stream>>>(h_bf, wqkv_b, bqkv, qkvb, vtb, 512);
  attn_mfma<<<dim3(64, 16), B256, 0, stream>>>(qkvb, vtb, tb_bf);
  gemm_bf16<1><<<dim3(4, 64), B256, 0, stream>>>(tb_bf, wo_b, bo, xc, 512, 512, xc, 1.0f);

  // ---- Conv module: xc += conv(xc) ----
  ln512_kernel<1><<<dim3(NTOK / 4), B256, 0, stream>>>(xc, conv_g, conv_b, h_bf);
  gemm_glu_bf16<1><<<dim3(16, 64), B256, 0, stream>>>(h_bf, pw1w_b, pw1_b, g_bf, 1024, 512);
  dwconv_kernel<<<dim3(16, 16, 8), B256, 0, stream>>>(g_bf, dw_w, dw_b, bn_g, bn_b, bn_m, bn_v, cv_bf);
  gemm_bf16<1><<<dim3(4, 64), B256, 0, stream>>>(cv_bf, pw2w_b, pw2_b, xc, 512, 1024, xc, 1.0f);

  // ---- FF2: xc += 0.5*ff(xc) ----
  ln512_kernel<1><<<dim3(NTOK / 4), B256, 0, stream>>>(xc, ff2_g, ff2_b, h_bf);
  gemm_glu_bf16<0><<<dim3(32, 64), B256, 0, stream>>>(h_bf, ff2win_b, ff2_bin, g_bf, 2048, 512);
  gemm_bf16<1><<<dim3(4, 64), B256, 0, stream>>>(g_bf, ff2wout_b, ff2_bout, xc, 512, 2048, xc, 0.5f);

  // ---- Final LN ----
  ln512_kernel<0><<<dim3(NTOK / 4), B256, 0, stream>>>(xc, fn_g, fn_b, outp);
}

// Round 9
// 615.864 us; speedup vs baseline: 1.0898x; 1.0898x over previous
//
#include <hip/hip_runtime.h>

#define SEQ   1024
#define BATCH 8
#define DIM   512
#define NTOK  (SEQ * BATCH)

typedef unsigned short ushort_t;
typedef unsigned int uint_t;
typedef __attribute__((ext_vector_type(8))) short s16x8;
typedef __attribute__((ext_vector_type(4))) float f32x4;

union F4 { float4 v; float f[4]; };

__device__ __forceinline__ float sigmoid_f(float x) { return 1.0f / (1.0f + expf(-x)); }
__device__ __forceinline__ float silu_f(float x)    { return x * sigmoid_f(x); }

__device__ __forceinline__ ushort_t f2bf(float x) {
  uint_t u = __float_as_uint(x);
  return (ushort_t)((u + 0x7FFFu + ((u >> 16) & 1u)) >> 16);
}
__device__ __forceinline__ float bf2f(ushort_t h) {
  return __uint_as_float(((uint_t)h) << 16);
}

__device__ __forceinline__ void gload16(const void* g, void* l) {
  __builtin_amdgcn_global_load_lds(
      (const __attribute__((address_space(1))) void*)g,
      (__attribute__((address_space(3))) void*)l,
      16, 0, 0);
}

// ---------------------------------------------------------------------------
// Fused f32 -> bf16 cast over 8 segments (one launch for all weight casts).
// ---------------------------------------------------------------------------
struct CastArgs {
  const float* src[8];
  ushort_t*    dst[8];
  int          cum8[8];   // start (in 8-elem units) of each segment
};

__global__ __launch_bounds__(256) void f2b_multi(CastArgs a, int total8)
{
  const int i = blockIdx.x * 256 + threadIdx.x;
  if (i >= total8) return;
  int s = 0;
  #pragma unroll
  for (int k = 1; k < 8; ++k) s += (i >= a.cum8[k]) ? 1 : 0;
  const int j = i - a.cum8[s];
  const float* src = a.src[s] + (size_t)j * 8;
  F4 x0, x1;
  x0.v = *(const float4*)(src);
  x1.v = *(const float4*)(src + 4);
  uint4 o;
  o.x = (uint_t)f2bf(x0.f[0]) | ((uint_t)f2bf(x0.f[1]) << 16);
  o.y = (uint_t)f2bf(x0.f[2]) | ((uint_t)f2bf(x0.f[3]) << 16);
  o.z = (uint_t)f2bf(x1.f[0]) | ((uint_t)f2bf(x1.f[1]) << 16);
  o.w = (uint_t)f2bf(x1.f[2]) | ((uint_t)f2bf(x1.f[3]) << 16);
  *(uint4*)(a.dst[s] + (size_t)j * 8) = o;
}

// ---------------------------------------------------------------------------
// LayerNorm (512). One wave per row, 4 rows/block, no cross-wave sync.
// BF=1: bf16 out, BF=0: fp32 out.
// ---------------------------------------------------------------------------
template <int BF>
__global__ __launch_bounds__(256) void ln512_kernel(
    const float* __restrict__ in, const float* __restrict__ g,
    const float* __restrict__ b, void* __restrict__ outv)
{
  const int row = blockIdx.x * 4 + (threadIdx.x >> 6);
  const int l   = threadIdx.x & 63;
  const float* rp = in + (size_t)row * DIM + l * 8;
  F4 v0, v1;
  v0.v = *(const float4*)(rp);
  v1.v = *(const float4*)(rp + 4);
  float sum = 0.f, sq = 0.f;
  #pragma unroll
  for (int j = 0; j < 4; ++j) { sum += v0.f[j] + v1.f[j];
                                sq  += v0.f[j]*v0.f[j] + v1.f[j]*v1.f[j]; }
  #pragma unroll
  for (int m = 32; m >= 1; m >>= 1) {
    sum += __shfl_xor(sum, m, 64);
    sq  += __shfl_xor(sq,  m, 64);
  }
  const float mu   = sum * (1.0f / DIM);
  const float var  = sq * (1.0f / DIM) - mu * mu;
  const float rinv = rsqrtf(var + 1e-5f);
  F4 g0, g1, b0, b1;
  g0.v = *(const float4*)(g + l * 8);     g1.v = *(const float4*)(g + l * 8 + 4);
  b0.v = *(const float4*)(b + l * 8);     b1.v = *(const float4*)(b + l * 8 + 4);
  float o[8];
  #pragma unroll
  for (int j = 0; j < 4; ++j) {
    o[j]     = (v0.f[j] - mu) * rinv * g0.f[j] + b0.f[j];
    o[4 + j] = (v1.f[j] - mu) * rinv * g1.f[j] + b1.f[j];
  }
  if (BF) {
    uint4 u;
    u.x = (uint_t)f2bf(o[0]) | ((uint_t)f2bf(o[1]) << 16);
    u.y = (uint_t)f2bf(o[2]) | ((uint_t)f2bf(o[3]) << 16);
    u.z = (uint_t)f2bf(o[4]) | ((uint_t)f2bf(o[5]) << 16);
    u.w = (uint_t)f2bf(o[6]) | ((uint_t)f2bf(o[7]) << 16);
    *(uint4*)((ushort_t*)outv + (size_t)row * DIM + l * 8) = u;
  } else {
    F4 w0, w1;
    #pragma unroll
    for (int j = 0; j < 4; ++j) { w0.f[j] = o[j]; w1.f[j] = o[4 + j]; }
    *(float4*)((float*)outv + (size_t)row * DIM + l * 8)     = w0.v;
    *(float4*)((float*)outv + (size_t)row * DIM + l * 8 + 4) = w1.v;
  }
}

// ---------------------------------------------------------------------------
// bf16 NT GEMM: out[M,N] = A*W^T + bias. EPI0: fp32 out. EPI1: fp32 out with
// residual (res + alpha*(acc+bias)).
// ---------------------------------------------------------------------------
template <int EPI>
__global__ __launch_bounds__(256) void gemm_bf16(
    const ushort_t* __restrict__ A, const ushort_t* __restrict__ W,
    const float* __restrict__ bias, float* __restrict__ out,
    int N, int K, const float* __restrict__ res, float alpha)
{
  __shared__ ushort_t As[128 * 32];
  __shared__ ushort_t Ws[128 * 32];
  const int t    = threadIdx.x;
  const int lane = t & 63;
  const int w    = t >> 6;
  const int wm   = w >> 1, wn = w & 1;
  const int m0   = blockIdx.y << 7, n0 = blockIdx.x << 7;

  f32x4 acc[4][4] = {};

  const int lds0 = __builtin_amdgcn_readfirstlane((w * 64) * 16);
  const int lds1 = __builtin_amdgcn_readfirstlane((256 + w * 64) * 16);
  const int r0c  = t >> 2;
  const int r1c  = 64 + (t >> 2);
  const int cc   = (t & 3) << 3;

  for (int k0 = 0; k0 < K; k0 += 32) {
    gload16(A + (size_t)(m0 + r0c) * K + k0 + cc, (char*)As + lds0);
    gload16(A + (size_t)(m0 + r1c) * K + k0 + cc, (char*)As + lds1);
    gload16(W + (size_t)(n0 + r0c) * K + k0 + cc, (char*)Ws + lds0);
    gload16(W + (size_t)(n0 + r1c) * K + k0 + cc, (char*)Ws + lds1);
    __syncthreads();
    s16x8 a[4], b[4];
    #pragma unroll
    for (int i = 0; i < 4; ++i)
      a[i] = *(const s16x8*)&As[(wm * 64 + i * 16 + (lane & 15)) * 32 + ((lane >> 4) << 3)];
    #pragma unroll
    for (int j = 0; j < 4; ++j)
      b[j] = *(const s16x8*)&Ws[(wn * 64 + j * 16 + (lane & 15)) * 32 + ((lane >> 4) << 3)];
    #pragma unroll
    for (int i = 0; i < 4; ++i)
      #pragma unroll
      for (int j = 0; j < 4; ++j)
        acc[i][j] = __builtin_amdgcn_mfma_f32_16x16x32_bf16(a[i], b[j], acc[i][j], 0, 0, 0);
    __syncthreads();
  }

  #pragma unroll
  for (int i = 0; i < 4; ++i) {
    #pragma unroll
    for (int j = 0; j < 4; ++j) {
      const int col  = n0 + wn * 64 + j * 16 + (lane & 15);
      const int rowb = m0 + wm * 64 + i * 16 + ((lane >> 4) << 2);
      const float bc = bias[col];
      #pragma unroll
      for (int r = 0; r < 4; ++r) {
        const size_t idx = (size_t)(rowb + r) * N + col;
        float v = acc[i][j][r] + bc;
        if (EPI == 1) v = res[idx] + alpha * v;
        out[idx] = v;
      }
    }
  }
}

// ---------------------------------------------------------------------------
// QKV GEMM: bf16 out. Q,K cols (<1024) -> qkvb[tok][1536]; V cols -> Vt
// transposed: Vt[(b*8+h)*64 + d][s] (bf16).
// ---------------------------------------------------------------------------
__global__ __launch_bounds__(256) void gemm_qkv_bf16(
    const ushort_t* __restrict__ A, const ushort_t* __restrict__ W,
    const float* __restrict__ bias, ushort_t* __restrict__ qkvb,
    ushort_t* __restrict__ Vt, int K)
{
  const int N = 1536;
  __shared__ ushort_t As[128 * 32];
  __shared__ ushort_t Ws[128 * 32];
  const int t    = threadIdx.x;
  const int lane = t & 63;
  const int w    = t >> 6;
  const int wm   = w >> 1, wn = w & 1;
  const int m0   = blockIdx.y << 7, n0 = blockIdx.x << 7;

  f32x4 acc[4][4] = {};

  const int lds0 = __builtin_amdgcn_readfirstlane((w * 64) * 16);
  const int lds1 = __builtin_amdgcn_readfirstlane((256 + w * 64) * 16);
  const int r0c  = t >> 2;
  const int r1c  = 64 + (t >> 2);
  const int cc   = (t & 3) << 3;

  for (int k0 = 0; k0 < K; k0 += 32) {
    gload16(A + (size_t)(m0 + r0c) * K + k0 + cc, (char*)As + lds0);
    gload16(A + (size_t)(m0 + r1c) * K + k0 + cc, (char*)As + lds1);
    gload16(W + (size_t)(n0 + r0c) * K + k0 + cc, (char*)Ws + lds0);
    gload16(W + (size_t)(n0 + r1c) * K + k0 + cc, (char*)Ws + lds1);
    __syncthreads();
    s16x8 a[4], b[4];
    #pragma unroll
    for (int i = 0; i < 4; ++i)
      a[i] = *(const s16x8*)&As[(wm * 64 + i * 16 + (lane & 15)) * 32 + ((lane >> 4) << 3)];
    #pragma unroll
    for (int j = 0; j < 4; ++j)
      b[j] = *(const s16x8*)&Ws[(wn * 64 + j * 16 + (lane & 15)) * 32 + ((lane >> 4) << 3)];
    #pragma unroll
    for (int i = 0; i < 4; ++i)
      #pragma unroll
      for (int j = 0; j < 4; ++j)
        acc[i][j] = __builtin_amdgcn_mfma_f32_16x16x32_bf16(a[i], b[j], acc[i][j], 0, 0, 0);
    __syncthreads();
  }

  #pragma unroll
  for (int i = 0; i < 4; ++i) {
    #pragma unroll
    for (int j = 0; j < 4; ++j) {
      const int col  = n0 + wn * 64 + j * 16 + (lane & 15);
      const int rowb = m0 + wm * 64 + i * 16 + ((lane >> 4) << 2);
      const float bc = bias[col];
      if (col < 1024) {
        #pragma unroll
        for (int r = 0; r < 4; ++r)
          qkvb[(size_t)(rowb + r) * N + col] = f2bf(acc[i][j][r] + bc);
      } else {
        const int vc = col - 1024;
        const int hh = vc >> 6, d = vc & 63;
        const int bb = rowb >> 10, s = rowb & 1023;
        ushort4 o;
        o.x = f2bf(acc[i][j][0] + bc);
        o.y = f2bf(acc[i][j][1] + bc);
        o.z = f2bf(acc[i][j][2] + bc);
        o.w = f2bf(acc[i][j][3] + bc);
        *(ushort4*)&Vt[(size_t)((bb * 8 + hh) * 64 + d) * 1024 + s] = o;
      }
    }
  }
}

// ---------------------------------------------------------------------------
// bf16 GLU GEMM. CGLU=0: silu(a)*c (FF); CGLU=1: a*sigmoid(c) (conv).
// ---------------------------------------------------------------------------
template <int CGLU>
__global__ __launch_bounds__(256) void gemm_glu_bf16(
    const ushort_t* __restrict__ A, const ushort_t* __restrict__ W,
    const float* __restrict__ bias, ushort_t* __restrict__ out,
    int NG, int K)
{
  __shared__ ushort_t As[128 * 32];
  __shared__ ushort_t Was[64 * 32];
  __shared__ ushort_t Wcs[64 * 32];
  const int t    = threadIdx.x;
  const int lane = t & 63;
  const int w    = t >> 6;
  const int wm   = w >> 1, wn = w & 1;
  const int m0   = blockIdx.y << 7, n0 = blockIdx.x << 6;

  f32x4 acca[4][2] = {};
  f32x4 accc[4][2] = {};

  const int lds0 = __builtin_amdgcn_readfirstlane((w * 64) * 16);
  const int lds1 = __builtin_amdgcn_readfirstlane((256 + w * 64) * 16);
  const int r0c  = t >> 2;
  const int r1c  = 64 + (t >> 2);
  const int cc   = (t & 3) << 3;

  const ushort_t* Wc = W + (size_t)NG * K;

  for (int k0 = 0; k0 < K; k0 += 32) {
    gload16(A  + (size_t)(m0 + r0c) * K + k0 + cc, (char*)As  + lds0);
    gload16(A  + (size_t)(m0 + r1c) * K + k0 + cc, (char*)As  + lds1);
    gload16(W  + (size_t)(n0 + r0c) * K + k0 + cc, (char*)Was + lds0);
    gload16(Wc + (size_t)(n0 + r0c) * K + k0 + cc, (char*)Wcs + lds0);
    __syncthreads();
    s16x8 a[4], ba[2], bc[2];
    #pragma unroll
    for (int i = 0; i < 4; ++i)
      a[i] = *(const s16x8*)&As[(wm * 64 + i * 16 + (lane & 15)) * 32 + ((lane >> 4) << 3)];
    #pragma unroll
    for (int j = 0; j < 2; ++j) {
      const int roff = (wn * 32 + j * 16 + (lane & 15)) * 32 + ((lane >> 4) << 3);
      ba[j] = *(const s16x8*)&Was[roff];
      bc[j] = *(const s16x8*)&Wcs[roff];
    }
    #pragma unroll
    for (int i = 0; i < 4; ++i)
      #pragma unroll
      for (int j = 0; j < 2; ++j) {
        acca[i][j] = __builtin_amdgcn_mfma_f32_16x16x32_bf16(a[i], ba[j], acca[i][j], 0, 0, 0);
        accc[i][j] = __builtin_amdgcn_mfma_f32_16x16x32_bf16(a[i], bc[j], accc[i][j], 0, 0, 0);
      }
    __syncthreads();
  }

  #pragma unroll
  for (int i = 0; i < 4; ++i) {
    #pragma unroll
    for (int j = 0; j < 2; ++j) {
      const int col  = n0 + wn * 32 + j * 16 + (lane & 15);
      const int rowb = m0 + wm * 64 + i * 16 + ((lane >> 4) << 2);
      const float b1 = bias[col];
      const float b2 = bias[NG + col];
      #pragma unroll
      for (int r = 0; r < 4; ++r) {
        const float av = acca[i][j][r] + b1;
        const float cv = accc[i][j][r] + b2;
        const float o  = CGLU ? (av * sigmoid_f(cv)) : (silu_f(av) * cv);
        out[(size_t)(rowb + r) * NG + col] = f2bf(o);
      }
    }
  }
}

// ---------------------------------------------------------------------------
// MFMA flash attention (bf16 inputs, fp32 softmax/acc).
// ---------------------------------------------------------------------------
__global__ __launch_bounds__(256) void attn_mfma(
    const ushort_t* __restrict__ qkv, const ushort_t* __restrict__ Vt,
    ushort_t* __restrict__ out)
{
  __shared__ ushort_t Ks[64 * 64];
  __shared__ ushort_t Vs[64 * 64];
  __shared__ ushort_t Ps[4][16 * 64];

  const int t    = threadIdx.x;
  const int lane = t & 63;
  const int w    = t >> 6;
  const int i    = lane & 15;
  const int g    = lane >> 4;
  const int bh   = blockIdx.x;
  const int b    = bh >> 3, h = bh & 7;
  const int qt   = blockIdx.y;

  s16x8 qf[2];
  {
    const ushort_t* qrow = qkv + (size_t)(b * SEQ + qt * 64 + w * 16 + i) * 1536 + h * 64;
    qf[0] = *(const s16x8*)(qrow + g * 8);
    qf[1] = *(const s16x8*)(qrow + 32 + g * 8);
  }

  float m_[4], l_[4];
  f32x4 po[4] = {};
  #pragma unroll
  for (int r = 0; r < 4; ++r) { m_[r] = -1e30f; l_[r] = 0.0f; }

  const int e0   = w * 2;
  const int off0 = __builtin_amdgcn_readfirstlane(e0 * 1024);
  const int off1 = __builtin_amdgcn_readfirstlane(e0 * 1024 + 1024);

  for (int kvt = 0; kvt < 16; ++kvt) {
    __syncthreads();
    {
      const int s_a = e0 * 64 + lane;
      const int ra = s_a >> 3, ca = (s_a & 7) ^ (ra & 7);
      const int s_b = s_a + 64;
      const int rb = s_b >> 3, cb2 = (s_b & 7) ^ (rb & 7);
      gload16(qkv + (size_t)(b * SEQ + kvt * 64 + ra) * 1536 + 512 + h * 64 + ca * 8,
              (char*)Ks + off0);
      gload16(qkv + (size_t)(b * SEQ + kvt * 64 + rb) * 1536 + 512 + h * 64 + cb2 * 8,
              (char*)Ks + off1);
      gload16(Vt + (size_t)(bh * 64 + ra) * SEQ + kvt * 64 + ca * 8,
              (char*)Vs + off0);
      gload16(Vt + (size_t)(bh * 64 + rb) * SEQ + kvt * 64 + cb2 * 8,
              (char*)Vs + off1);
    }
    __syncthreads();

    f32x4 sc[4] = {};
    #pragma unroll
    for (int jj = 0; jj < 4; ++jj) {
      const int row = jj * 16 + i;
      #pragma unroll
      for (int dd = 0; dd < 2; ++dd) {
        const int byteoff = row * 128 + ((dd * 64 + g * 16) ^ ((row & 7) << 4));
        const s16x8 kf = *(const s16x8*)((const char*)Ks + byteoff);
        sc[jj] = __builtin_amdgcn_mfma_f32_16x16x32_bf16(qf[dd], kf, sc[jj], 0, 0, 0);
      }
    }

    #pragma unroll
    for (int r = 0; r < 4; ++r) {
      float v0 = sc[0][r] * 0.125f, v1 = sc[1][r] * 0.125f;
      float v2 = sc[2][r] * 0.125f, v3 = sc[3][r] * 0.125f;
      float mx = fmaxf(fmaxf(v0, v1), fmaxf(v2, v3));
      mx = fmaxf(mx, __shfl_xor(mx, 1));
      mx = fmaxf(mx, __shfl_xor(mx, 2));
      mx = fmaxf(mx, __shfl_xor(mx, 4));
      mx = fmaxf(mx, __shfl_xor(mx, 8));
      const float mn = fmaxf(m_[r], mx);
      const float al = __expf(m_[r] - mn);
      const float p0 = __expf(v0 - mn), p1 = __expf(v1 - mn);
      const float p2 = __expf(v2 - mn), p3 = __expf(v3 - mn);
      float rs = p0 + p1 + p2 + p3;
      rs += __shfl_xor(rs, 1); rs += __shfl_xor(rs, 2);
      rs += __shfl_xor(rs, 4); rs += __shfl_xor(rs, 8);
      l_[r] = l_[r] * al + rs;
      m_[r] = mn;
      #pragma unroll
      for (int dt = 0; dt < 4; ++dt) po[dt][r] *= al;
      const int q = 4 * g + r;
      const int key = (q & 7) << 4;
      ushort_t* pb = &Ps[w][0];
      ((ushort_t*)((char*)pb + q * 128 + ((2 * i) ^ key)))[0]       = f2bf(p0);
      ((ushort_t*)((char*)pb + q * 128 + ((32 + 2 * i) ^ key)))[0]  = f2bf(p1);
      ((ushort_t*)((char*)pb + q * 128 + ((64 + 2 * i) ^ key)))[0]  = f2bf(p2);
      ((ushort_t*)((char*)pb + q * 128 + ((96 + 2 * i) ^ key)))[0]  = f2bf(p3);
    }

    #pragma unroll
    for (int kc = 0; kc < 2; ++kc) {
      const int pbyte = i * 128 + ((kc * 64 + g * 16) ^ ((i & 7) << 4));
      const s16x8 pf = *(const s16x8*)((const char*)&Ps[w][0] + pbyte);
      #pragma unroll
      for (int dt = 0; dt < 4; ++dt) {
        const int vrow = dt * 16 + i;
        const int vbyte = vrow * 128 + ((kc * 64 + g * 16) ^ ((vrow & 7) << 4));
        const s16x8 vf = *(const s16x8*)((const char*)Vs + vbyte);
        po[dt] = __builtin_amdgcn_mfma_f32_16x16x32_bf16(pf, vf, po[dt], 0, 0, 0);
      }
    }
  }

  #pragma unroll
  for (int r = 0; r < 4; ++r) {
    const float inv = 1.0f / l_[r];
    const size_t row = (size_t)(b * SEQ + qt * 64 + w * 16 + 4 * g + r);
    #pragma unroll
    for (int dt = 0; dt < 4; ++dt)
      out[row * 512 + h * 64 + dt * 16 + i] = f2bf(po[dt][r] * inv);
  }
}

// ---------------------------------------------------------------------------
// Grouped conv1d (K=31) + bias + BN + SiLU. bf16 in/out, fp32 internal.
// lane = channel (round-3 mapping); sliding-window tap loop: v[a] loaded
// once, dies immediately; wt[] live 16 iters; live set ~55 VGPR.
// ---------------------------------------------------------------------------
__global__ __launch_bounds__(256) void dwconv_kernel(
    const ushort_t* __restrict__ in, const float* __restrict__ w,
    const float* __restrict__ dwb, const float* __restrict__ bng,
    const float* __restrict__ bnb, const float* __restrict__ bnm,
    const float* __restrict__ bnv, ushort_t* __restrict__ out)
{
  __shared__ __align__(16) float tile[94][64];
  const int s0 = blockIdx.x << 6;
  const int c0 = blockIdx.y << 6;
  const int b  = blockIdx.z;
  const int t  = threadIdx.x;

  // ---- stage input (bf16 -> f32) ----
  {
    const int cl4 = (t & 15) << 2;
    #pragma unroll
    for (int it = 0; it < 6; ++it) {
      const int rr = it * 16 + (t >> 4);
      if (rr < 94) {
        const int gs = s0 - 15 + rr;
        float4 fv = make_float4(0.f, 0.f, 0.f, 0.f);
        if (gs >= 0 && gs < SEQ) {
          ushort4 uv = *(const ushort4*)(in + (size_t)(b * SEQ + gs) * 1024 + c0 + cl4);
          fv = make_float4(bf2f(uv.x), bf2f(uv.y), bf2f(uv.z), bf2f(uv.w));
        }
        *(float4*)&tile[rr][cl4] = fv;
      }
    }
  }
  __syncthreads();

  const int c  = t & 63;            // channel within block
  const int sb = (t >> 6) << 4;     // wave -> 16 consecutive s-positions
  const int gc = c0 + c;

  float acc[16] = {};
  const float* wc = w + (size_t)gc * 248;   // [1024][8][31]
  for (int ci = 0; ci < 8; ++ci) {
    const int cl = (c & 56) | ci;
    const float* wp = wc + ci * 31;
    float wt[31];
    #pragma unroll
    for (int a = 0; a < 46; ++a) {
      const float va = tile[sb + a][cl];
      if (a < 31) wt[a] = wp[a];
      #pragma unroll
      for (int j = 0; j < 16; ++j) {
        if (j <= a && a - j <= 30)
          acc[j] = fmaf(wt[a - j], va, acc[j]);
      }
    }
  }

  const float bias = dwb[gc];
  const float mean = bnm[gc];
  const float rstd = rsqrtf(bnv[gc] + 1e-5f);
  const float gg   = bng[gc];
  const float bb2  = bnb[gc];
  #pragma unroll
  for (int j = 0; j < 16; ++j) {
    const int s = s0 + sb + j;
    float y = acc[j] + bias;
    y = (y - mean) * rstd * gg + bb2;
    out[(size_t)(b * SEQ + s) * 1024 + gc] = f2bf(silu_f(y));
  }
}

// ---------------------------------------------------------------------------
extern "C" void kernel_launch(void* const* d_in, const int* in_sizes, int n_in,
                              void* d_out, int out_size, void* d_ws, size_t ws_size,
                              hipStream_t stream)
{
  (void)in_sizes; (void)n_in; (void)out_size; (void)ws_size;
  const float* x        = (const float*)d_in[0];
  const float* ff1_g    = (const float*)d_in[1];
  const float* ff1_b    = (const float*)d_in[2];
  const float* ff1_win  = (const float*)d_in[3];
  const float* ff1_bin  = (const float*)d_in[4];
  const float* ff1_wout = (const float*)d_in[5];
  const float* ff1_bout = (const float*)d_in[6];
  const float* attn_g   = (const float*)d_in[7];
  const float* attn_b   = (const float*)d_in[8];
  const float* wqkv     = (const float*)d_in[9];
  const float* bqkv     = (const float*)d_in[10];
  const float* wo       = (const float*)d_in[11];
  const float* bo       = (const float*)d_in[12];
  const float* conv_g   = (const float*)d_in[13];
  const float* conv_b   = (const float*)d_in[14];
  const float* pw1_w    = (const float*)d_in[15];
  const float* pw1_b    = (const float*)d_in[16];
  const float* dw_w     = (const float*)d_in[17];
  const float* dw_b     = (const float*)d_in[18];
  const float* bn_g     = (const float*)d_in[19];
  const float* bn_b     = (const float*)d_in[20];
  const float* bn_m     = (const float*)d_in[21];
  const float* bn_v     = (const float*)d_in[22];
  const float* pw2_w    = (const float*)d_in[23];
  const float* pw2_b    = (const float*)d_in[24];
  const float* ff2_g    = (const float*)d_in[25];
  const float* ff2_b    = (const float*)d_in[26];
  const float* ff2_win  = (const float*)d_in[27];
  const float* ff2_bin  = (const float*)d_in[28];
  const float* ff2_wout = (const float*)d_in[29];
  const float* ff2_bout = (const float*)d_in[30];
  const float* fn_g     = (const float*)d_in[31];
  const float* fn_b     = (const float*)d_in[32];

  // workspace layout (bytes)
  char* wsb = (char*)d_ws;
  float*    xc    = (float*)(wsb);                           // 16 MB fp32 residual
  ushort_t* qkvb  = (ushort_t*)(wsb + (size_t)(16 << 20));   // 24 MB bf16 qkv (Q,K)
  ushort_t* vtb   = (ushort_t*)(wsb + (size_t)(40 << 20));   //  8 MB bf16 V^T
  ushort_t* h_bf  = (ushort_t*)(wsb + (size_t)(48 << 20));   //  8 MB bf16 LN out
  ushort_t* g_bf  = (ushort_t*)(wsb + (size_t)(56 << 20));   // 32 MB bf16 GLU out
  ushort_t* tb_bf = (ushort_t*)(wsb + (size_t)(88 << 20));   //  8 MB bf16 attn out
  ushort_t* cv_bf = (ushort_t*)(wsb + (size_t)(96 << 20));   // 16 MB bf16 conv out
  ushort_t* wb    = (ushort_t*)(wsb + (size_t)(112 << 20));  // ~18 MB bf16 weights

  ushort_t* ff1win_b  = wb;
  ushort_t* ff1wout_b = ff1win_b + 4096 * 512;
  ushort_t* wqkv_b    = ff1wout_b + 512 * 2048;
  ushort_t* wo_b      = wqkv_b + 1536 * 512;
  ushort_t* pw1w_b    = wo_b + 512 * 512;
  ushort_t* pw2w_b    = pw1w_b + 2048 * 512;
  ushort_t* ff2win_b  = pw2w_b + 512 * 1024;
  ushort_t* ff2wout_b = ff2win_b + 4096 * 512;

  float* outp = (float*)d_out;
  const dim3 B256(256);

  // ---- fused weight casts (one launch) ----
  {
    CastArgs a;
    const float* srcs[8] = {ff1_win, ff1_wout, wqkv, wo, pw1_w, pw2_w, ff2_win, ff2_wout};
    ushort_t*    dsts[8] = {ff1win_b, ff1wout_b, wqkv_b, wo_b, pw1w_b, pw2w_b, ff2win_b, ff2wout_b};
    const int    ns[8]   = {4096*512, 512*2048, 1536*512, 512*512,
                            2048*512, 512*1024, 4096*512, 512*2048};
    int cum = 0;
    for (int i = 0; i < 8; ++i) {
      a.src[i] = srcs[i]; a.dst[i] = dsts[i]; a.cum8[i] = cum; cum += ns[i] / 8;
    }
    f2b_multi<<<dim3((cum + 255) / 256), B256, 0, stream>>>(a, cum);
  }

  // ---- FF1: xc = x + 0.5*ff(x) ----
  ln512_kernel<1><<<dim3(NTOK / 4), B256, 0, stream>>>(x, ff1_g, ff1_b, h_bf);
  gemm_glu_bf16<0><<<dim3(32, 64), B256, 0, stream>>>(h_bf, ff1win_b, ff1_bin, g_bf, 2048, 512);
  gemm_bf16<1><<<dim3(4, 64), B256, 0, stream>>>(g_bf, ff1wout_b, ff1_bout, xc, 512, 2048, x, 0.5f);

  // ---- Attention: xc += attn(xc) ----
  ln512_kernel<1><<<dim3(NTOK / 4), B256, 0, stream>>>(xc, attn_g, attn_b, h_bf);
  gemm_qkv_bf16<<<dim3(12, 64), B256, 0, stream>>>(h_bf, wqkv_b, bqkv, qkvb, vtb, 512);
  attn_mfma<<<dim3(64, 16), B256, 0, stream>>>(qkvb, vtb, tb_bf);
  gemm_bf16<1><<<dim3(4, 64), B256, 0, stream>>>(tb_bf, wo_b, bo, xc, 512, 512, xc, 1.0f);

  // ---- Conv module: xc += conv(xc) ----
  ln512_kernel<1><<<dim3(NTOK / 4), B256, 0, stream>>>(xc, conv_g, conv_b, h_bf);
  gemm_glu_bf16<1><<<dim3(16, 64), B256, 0, stream>>>(h_bf, pw1w_b, pw1_b, g_bf, 1024, 512);
  dwconv_kernel<<<dim3(16, 16, 8), B256, 0, stream>>>(g_bf, dw_w, dw_b, bn_g, bn_b, bn_m, bn_v, cv_bf);
  gemm_bf16<1><<<dim3(4, 64), B256, 0, stream>>>(cv_bf, pw2w_b, pw2_b, xc, 512, 1024, xc, 1.0f);

  // ---- FF2: xc += 0.5*ff(xc) ----
  ln512_kernel<1><<<dim3(NTOK / 4), B256, 0, stream>>>(xc, ff2_g, ff2_b, h_bf);
  gemm_glu_bf16<0><<<dim3(32, 64), B256, 0, stream>>>(h_bf, ff2win_b, ff2_bin, g_bf, 2048, 512);
  gemm_bf16<1><<<dim3(4, 64), B256, 0, stream>>>(g_bf, ff2wout_b, ff2_bout, xc, 512, 2048, xc, 0.5f);

  // ---- Final LN ----
  ln512_kernel<0><<<dim3(NTOK / 4), B256, 0, stream>>>(xc, fn_g, fn_b, outp);
}

// Round 11
// 566.536 us; speedup vs baseline: 1.1847x; 1.0871x over previous
//
#include <hip/hip_runtime.h>

#define SEQ   1024
#define BATCH 8
#define DIM   512
#define NTOK  (SEQ * BATCH)

typedef unsigned short ushort_t;
typedef unsigned int uint_t;
typedef __attribute__((ext_vector_type(8))) short s16x8;
typedef __attribute__((ext_vector_type(4))) float f32x4;

union F4 { float4 v; float f[4]; };

__device__ __forceinline__ float sigmoid_f(float x) { return 1.0f / (1.0f + expf(-x)); }
__device__ __forceinline__ float silu_f(float x)    { return x * sigmoid_f(x); }

__device__ __forceinline__ ushort_t f2bf(float x) {
  uint_t u = __float_as_uint(x);
  return (ushort_t)((u + 0x7FFFu + ((u >> 16) & 1u)) >> 16);
}
__device__ __forceinline__ float bf2f(ushort_t h) {
  return __uint_as_float(((uint_t)h) << 16);
}

__device__ __forceinline__ void gload16(const void* g, void* l) {
  __builtin_amdgcn_global_load_lds(
      (const __attribute__((address_space(1))) void*)g,
      (__attribute__((address_space(3))) void*)l,
      16, 0, 0);
}

// ---------------------------------------------------------------------------
// Fused f32 -> bf16 cast over 8 segments (one launch for all weight casts).
// ---------------------------------------------------------------------------
struct CastArgs {
  const float* src[8];
  ushort_t*    dst[8];
  int          cum8[8];   // start (in 8-elem units) of each segment
};

__global__ __launch_bounds__(256) void f2b_multi(CastArgs a, int total8)
{
  const int i = blockIdx.x * 256 + threadIdx.x;
  if (i >= total8) return;
  int s = 0;
  #pragma unroll
  for (int k = 1; k < 8; ++k) s += (i >= a.cum8[k]) ? 1 : 0;
  const int j = i - a.cum8[s];
  const float* src = a.src[s] + (size_t)j * 8;
  F4 x0, x1;
  x0.v = *(const float4*)(src);
  x1.v = *(const float4*)(src + 4);
  uint4 o;
  o.x = (uint_t)f2bf(x0.f[0]) | ((uint_t)f2bf(x0.f[1]) << 16);
  o.y = (uint_t)f2bf(x0.f[2]) | ((uint_t)f2bf(x0.f[3]) << 16);
  o.z = (uint_t)f2bf(x1.f[0]) | ((uint_t)f2bf(x1.f[1]) << 16);
  o.w = (uint_t)f2bf(x1.f[2]) | ((uint_t)f2bf(x1.f[3]) << 16);
  *(uint4*)(a.dst[s] + (size_t)j * 8) = o;
}

// ---------------------------------------------------------------------------
// LayerNorm (512). One wave per row, 4 rows/block, no cross-wave sync.
// BF=1: bf16 out, BF=0: fp32 out.
// ---------------------------------------------------------------------------
template <int BF>
__global__ __launch_bounds__(256) void ln512_kernel(
    const float* __restrict__ in, const float* __restrict__ g,
    const float* __restrict__ b, void* __restrict__ outv)
{
  const int row = blockIdx.x * 4 + (threadIdx.x >> 6);
  const int l   = threadIdx.x & 63;
  const float* rp = in + (size_t)row * DIM + l * 8;
  F4 v0, v1;
  v0.v = *(const float4*)(rp);
  v1.v = *(const float4*)(rp + 4);
  float sum = 0.f, sq = 0.f;
  #pragma unroll
  for (int j = 0; j < 4; ++j) { sum += v0.f[j] + v1.f[j];
                                sq  += v0.f[j]*v0.f[j] + v1.f[j]*v1.f[j]; }
  #pragma unroll
  for (int m = 32; m >= 1; m >>= 1) {
    sum += __shfl_xor(sum, m, 64);
    sq  += __shfl_xor(sq,  m, 64);
  }
  const float mu   = sum * (1.0f / DIM);
  const float var  = sq * (1.0f / DIM) - mu * mu;
  const float rinv = rsqrtf(var + 1e-5f);
  F4 g0, g1, b0, b1;
  g0.v = *(const float4*)(g + l * 8);     g1.v = *(const float4*)(g + l * 8 + 4);
  b0.v = *(const float4*)(b + l * 8);     b1.v = *(const float4*)(b + l * 8 + 4);
  float o[8];
  #pragma unroll
  for (int j = 0; j < 4; ++j) {
    o[j]     = (v0.f[j] - mu) * rinv * g0.f[j] + b0.f[j];
    o[4 + j] = (v1.f[j] - mu) * rinv * g1.f[j] + b1.f[j];
  }
  if (BF) {
    uint4 u;
    u.x = (uint_t)f2bf(o[0]) | ((uint_t)f2bf(o[1]) << 16);
    u.y = (uint_t)f2bf(o[2]) | ((uint_t)f2bf(o[3]) << 16);
    u.z = (uint_t)f2bf(o[4]) | ((uint_t)f2bf(o[5]) << 16);
    u.w = (uint_t)f2bf(o[6]) | ((uint_t)f2bf(o[7]) << 16);
    *(uint4*)((ushort_t*)outv + (size_t)row * DIM + l * 8) = u;
  } else {
    F4 w0, w1;
    #pragma unroll
    for (int j = 0; j < 4; ++j) { w0.f[j] = o[j]; w1.f[j] = o[4 + j]; }
    *(float4*)((float*)outv + (size_t)row * DIM + l * 8)     = w0.v;
    *(float4*)((float*)outv + (size_t)row * DIM + l * 8 + 4) = w1.v;
  }
}

// ---------------------------------------------------------------------------
// bf16 NT GEMM, double-buffered prefetch K-loop (T3 minimum-2-phase):
// STAGE(next) issued BEFORE compute; ONE __syncthreads per K-step (its
// implicit vmcnt(0) drain lands the prefetch after a full compute phase).
// EPI0: fp32 out. EPI1: fp32 out with residual (res + alpha*(acc+bias)).
// ---------------------------------------------------------------------------
template <int EPI>
__global__ __launch_bounds__(256) void gemm_bf16(
    const ushort_t* __restrict__ A, const ushort_t* __restrict__ W,
    const float* __restrict__ bias, float* __restrict__ out,
    int N, int K, const float* __restrict__ res, float alpha)
{
  __shared__ ushort_t As[2][128 * 32];
  __shared__ ushort_t Ws[2][128 * 32];
  const int t    = threadIdx.x;
  const int lane = t & 63;
  const int w    = t >> 6;
  const int wm   = w >> 1, wn = w & 1;
  const int m0   = blockIdx.y << 7, n0 = blockIdx.x << 7;

  f32x4 acc[4][4] = {};

  const int lds0 = __builtin_amdgcn_readfirstlane((w * 64) * 16);
  const int lds1 = __builtin_amdgcn_readfirstlane((256 + w * 64) * 16);
  const int r0c  = t >> 2;
  const int r1c  = 64 + (t >> 2);
  const int cc   = (t & 3) << 3;

  auto stage = [&](int buf, int k0) {
    gload16(A + (size_t)(m0 + r0c) * K + k0 + cc, (char*)As[buf] + lds0);
    gload16(A + (size_t)(m0 + r1c) * K + k0 + cc, (char*)As[buf] + lds1);
    gload16(W + (size_t)(n0 + r0c) * K + k0 + cc, (char*)Ws[buf] + lds0);
    gload16(W + (size_t)(n0 + r1c) * K + k0 + cc, (char*)Ws[buf] + lds1);
  };

  stage(0, 0);
  __syncthreads();
  int cur = 0;
  for (int k0 = 0; k0 < K; k0 += 32) {
    if (k0 + 32 < K) stage(cur ^ 1, k0 + 32);
    s16x8 a[4], b[4];
    #pragma unroll
    for (int i = 0; i < 4; ++i)
      a[i] = *(const s16x8*)&As[cur][(wm * 64 + i * 16 + (lane & 15)) * 32 + ((lane >> 4) << 3)];
    #pragma unroll
    for (int j = 0; j < 4; ++j)
      b[j] = *(const s16x8*)&Ws[cur][(wn * 64 + j * 16 + (lane & 15)) * 32 + ((lane >> 4) << 3)];
    #pragma unroll
    for (int i = 0; i < 4; ++i)
      #pragma unroll
      for (int j = 0; j < 4; ++j)
        acc[i][j] = __builtin_amdgcn_mfma_f32_16x16x32_bf16(a[i], b[j], acc[i][j], 0, 0, 0);
    __syncthreads();
    cur ^= 1;
  }

  #pragma unroll
  for (int i = 0; i < 4; ++i) {
    #pragma unroll
    for (int j = 0; j < 4; ++j) {
      const int col  = n0 + wn * 64 + j * 16 + (lane & 15);
      const int rowb = m0 + wm * 64 + i * 16 + ((lane >> 4) << 2);
      const float bc = bias[col];
      #pragma unroll
      for (int r = 0; r < 4; ++r) {
        const size_t idx = (size_t)(rowb + r) * N + col;
        float v = acc[i][j][r] + bc;
        if (EPI == 1) v = res[idx] + alpha * v;
        out[idx] = v;
      }
    }
  }
}

// ---------------------------------------------------------------------------
// QKV GEMM (double-buffered prefetch): bf16 out. Q,K cols (<1024) ->
// qkvb[tok][1536]; V cols -> Vt[(b*8+h)*64 + d][s] transposed (bf16).
// ---------------------------------------------------------------------------
__global__ __launch_bounds__(256) void gemm_qkv_bf16(
    const ushort_t* __restrict__ A, const ushort_t* __restrict__ W,
    const float* __restrict__ bias, ushort_t* __restrict__ qkvb,
    ushort_t* __restrict__ Vt, int K)
{
  const int N = 1536;
  __shared__ ushort_t As[2][128 * 32];
  __shared__ ushort_t Ws[2][128 * 32];
  const int t    = threadIdx.x;
  const int lane = t & 63;
  const int w    = t >> 6;
  const int wm   = w >> 1, wn = w & 1;
  const int m0   = blockIdx.y << 7, n0 = blockIdx.x << 7;

  f32x4 acc[4][4] = {};

  const int lds0 = __builtin_amdgcn_readfirstlane((w * 64) * 16);
  const int lds1 = __builtin_amdgcn_readfirstlane((256 + w * 64) * 16);
  const int r0c  = t >> 2;
  const int r1c  = 64 + (t >> 2);
  const int cc   = (t & 3) << 3;

  auto stage = [&](int buf, int k0) {
    gload16(A + (size_t)(m0 + r0c) * K + k0 + cc, (char*)As[buf] + lds0);
    gload16(A + (size_t)(m0 + r1c) * K + k0 + cc, (char*)As[buf] + lds1);
    gload16(W + (size_t)(n0 + r0c) * K + k0 + cc, (char*)Ws[buf] + lds0);
    gload16(W + (size_t)(n0 + r1c) * K + k0 + cc, (char*)Ws[buf] + lds1);
  };

  stage(0, 0);
  __syncthreads();
  int cur = 0;
  for (int k0 = 0; k0 < K; k0 += 32) {
    if (k0 + 32 < K) stage(cur ^ 1, k0 + 32);
    s16x8 a[4], b[4];
    #pragma unroll
    for (int i = 0; i < 4; ++i)
      a[i] = *(const s16x8*)&As[cur][(wm * 64 + i * 16 + (lane & 15)) * 32 + ((lane >> 4) << 3)];
    #pragma unroll
    for (int j = 0; j < 4; ++j)
      b[j] = *(const s16x8*)&Ws[cur][(wn * 64 + j * 16 + (lane & 15)) * 32 + ((lane >> 4) << 3)];
    #pragma unroll
    for (int i = 0; i < 4; ++i)
      #pragma unroll
      for (int j = 0; j < 4; ++j)
        acc[i][j] = __builtin_amdgcn_mfma_f32_16x16x32_bf16(a[i], b[j], acc[i][j], 0, 0, 0);
    __syncthreads();
    cur ^= 1;
  }

  #pragma unroll
  for (int i = 0; i < 4; ++i) {
    #pragma unroll
    for (int j = 0; j < 4; ++j) {
      const int col  = n0 + wn * 64 + j * 16 + (lane & 15);
      const int rowb = m0 + wm * 64 + i * 16 + ((lane >> 4) << 2);
      const float bc = bias[col];
      if (col < 1024) {
        #pragma unroll
        for (int r = 0; r < 4; ++r)
          qkvb[(size_t)(rowb + r) * N + col] = f2bf(acc[i][j][r] + bc);
      } else {
        const int vc = col - 1024;
        const int hh = vc >> 6, d = vc & 63;
        const int bb = rowb >> 10, s = rowb & 1023;
        ushort4 o;
        o.x = f2bf(acc[i][j][0] + bc);
        o.y = f2bf(acc[i][j][1] + bc);
        o.z = f2bf(acc[i][j][2] + bc);
        o.w = f2bf(acc[i][j][3] + bc);
        *(ushort4*)&Vt[(size_t)((bb * 8 + hh) * 64 + d) * 1024 + s] = o;
      }
    }
  }
}

// ---------------------------------------------------------------------------
// bf16 GLU GEMM (double-buffered prefetch).
// CGLU=0: silu(a)*c (FF); CGLU=1: a*sigmoid(c) (conv).
// ---------------------------------------------------------------------------
template <int CGLU>
__global__ __launch_bounds__(256) void gemm_glu_bf16(
    const ushort_t* __restrict__ A, const ushort_t* __restrict__ W,
    const float* __restrict__ bias, ushort_t* __restrict__ out,
    int NG, int K)
{
  __shared__ ushort_t As[2][128 * 32];
  __shared__ ushort_t Was[2][64 * 32];
  __shared__ ushort_t Wcs[2][64 * 32];
  const int t    = threadIdx.x;
  const int lane = t & 63;
  const int w    = t >> 6;
  const int wm   = w >> 1, wn = w & 1;
  const int m0   = blockIdx.y << 7, n0 = blockIdx.x << 6;

  f32x4 acca[4][2] = {};
  f32x4 accc[4][2] = {};

  const int lds0 = __builtin_amdgcn_readfirstlane((w * 64) * 16);
  const int lds1 = __builtin_amdgcn_readfirstlane((256 + w * 64) * 16);
  const int r0c  = t >> 2;
  const int r1c  = 64 + (t >> 2);
  const int cc   = (t & 3) << 3;

  const ushort_t* Wc = W + (size_t)NG * K;

  auto stage = [&](int buf, int k0) {
    gload16(A  + (size_t)(m0 + r0c) * K + k0 + cc, (char*)As[buf]  + lds0);
    gload16(A  + (size_t)(m0 + r1c) * K + k0 + cc, (char*)As[buf]  + lds1);
    gload16(W  + (size_t)(n0 + r0c) * K + k0 + cc, (char*)Was[buf] + lds0);
    gload16(Wc + (size_t)(n0 + r0c) * K + k0 + cc, (char*)Wcs[buf] + lds0);
  };

  stage(0, 0);
  __syncthreads();
  int cur = 0;
  for (int k0 = 0; k0 < K; k0 += 32) {
    if (k0 + 32 < K) stage(cur ^ 1, k0 + 32);
    s16x8 a[4], ba[2], bc[2];
    #pragma unroll
    for (int i = 0; i < 4; ++i)
      a[i] = *(const s16x8*)&As[cur][(wm * 64 + i * 16 + (lane & 15)) * 32 + ((lane >> 4) << 3)];
    #pragma unroll
    for (int j = 0; j < 2; ++j) {
      const int roff = (wn * 32 + j * 16 + (lane & 15)) * 32 + ((lane >> 4) << 3);
      ba[j] = *(const s16x8*)&Was[cur][roff];
      bc[j] = *(const s16x8*)&Wcs[cur][roff];
    }
    #pragma unroll
    for (int i = 0; i < 4; ++i)
      #pragma unroll
      for (int j = 0; j < 2; ++j) {
        acca[i][j] = __builtin_amdgcn_mfma_f32_16x16x32_bf16(a[i], ba[j], acca[i][j], 0, 0, 0);
        accc[i][j] = __builtin_amdgcn_mfma_f32_16x16x32_bf16(a[i], bc[j], accc[i][j], 0, 0, 0);
      }
    __syncthreads();
    cur ^= 1;
  }

  #pragma unroll
  for (int i = 0; i < 4; ++i) {
    #pragma unroll
    for (int j = 0; j < 2; ++j) {
      const int col  = n0 + wn * 32 + j * 16 + (lane & 15);
      const int rowb = m0 + wm * 64 + i * 16 + ((lane >> 4) << 2);
      const float b1 = bias[col];
      const float b2 = bias[NG + col];
      #pragma unroll
      for (int r = 0; r < 4; ++r) {
        const float av = acca[i][j][r] + b1;
        const float cv = accc[i][j][r] + b2;
        const float o  = CGLU ? (av * sigmoid_f(cv)) : (silu_f(av) * cv);
        out[(size_t)(rowb + r) * NG + col] = f2bf(o);
      }
    }
  }
}

// ---------------------------------------------------------------------------
// MFMA flash attention (bf16 inputs, fp32 softmax/acc), double-buffered K/V
// prefetch: next tile's loads fly during QK^T + softmax + PV of the current.
// ---------------------------------------------------------------------------
__global__ __launch_bounds__(256) void attn_mfma(
    const ushort_t* __restrict__ qkv, const ushort_t* __restrict__ Vt,
    ushort_t* __restrict__ out)
{
  __shared__ ushort_t Ks[2][64 * 64];
  __shared__ ushort_t Vs[2][64 * 64];
  __shared__ ushort_t Ps[4][16 * 64];

  const int t    = threadIdx.x;
  const int lane = t & 63;
  const int w    = t >> 6;
  const int i    = lane & 15;
  const int g    = lane >> 4;
  const int bh   = blockIdx.x;
  const int b    = bh >> 3, h = bh & 7;
  const int qt   = blockIdx.y;

  s16x8 qf[2];
  {
    const ushort_t* qrow = qkv + (size_t)(b * SEQ + qt * 64 + w * 16 + i) * 1536 + h * 64;
    qf[0] = *(const s16x8*)(qrow + g * 8);
    qf[1] = *(const s16x8*)(qrow + 32 + g * 8);
  }

  float m_[4], l_[4];
  f32x4 po[4] = {};
  #pragma unroll
  for (int r = 0; r < 4; ++r) { m_[r] = -1e30f; l_[r] = 0.0f; }

  const int e0   = w * 2;
  const int off0 = __builtin_amdgcn_readfirstlane(e0 * 1024);
  const int off1 = __builtin_amdgcn_readfirstlane(e0 * 1024 + 1024);

  auto stageKV = [&](int buf, int kvt) {
    const int s_a = e0 * 64 + lane;
    const int ra = s_a >> 3, ca = (s_a & 7) ^ (ra & 7);
    const int s_b = s_a + 64;
    const int rb = s_b >> 3, cb2 = (s_b & 7) ^ (rb & 7);
    gload16(qkv + (size_t)(b * SEQ + kvt * 64 + ra) * 1536 + 512 + h * 64 + ca * 8,
            (char*)Ks[buf] + off0);
    gload16(qkv + (size_t)(b * SEQ + kvt * 64 + rb) * 1536 + 512 + h * 64 + cb2 * 8,
            (char*)Ks[buf] + off1);
    gload16(Vt + (size_t)(bh * 64 + ra) * SEQ + kvt * 64 + ca * 8,
            (char*)Vs[buf] + off0);
    gload16(Vt + (size_t)(bh * 64 + rb) * SEQ + kvt * 64 + cb2 * 8,
            (char*)Vs[buf] + off1);
  };

  stageKV(0, 0);
  __syncthreads();
  int cur = 0;

  for (int kvt = 0; kvt < 16; ++kvt) {
    if (kvt + 1 < 16) stageKV(cur ^ 1, kvt + 1);

    // ---- QK^T on Ks[cur] ----
    f32x4 sc[4] = {};
    #pragma unroll
    for (int jj = 0; jj < 4; ++jj) {
      const int row = jj * 16 + i;
      #pragma unroll
      for (int dd = 0; dd < 2; ++dd) {
        const int byteoff = row * 128 + ((dd * 64 + g * 16) ^ ((row & 7) << 4));
        const s16x8 kf = *(const s16x8*)((const char*)Ks[cur] + byteoff);
        sc[jj] = __builtin_amdgcn_mfma_f32_16x16x32_bf16(qf[dd], kf, sc[jj], 0, 0, 0);
      }
    }

    // ---- online softmax (scale 1/8) ----
    #pragma unroll
    for (int r = 0; r < 4; ++r) {
      float v0 = sc[0][r] * 0.125f, v1 = sc[1][r] * 0.125f;
      float v2 = sc[2][r] * 0.125f, v3 = sc[3][r] * 0.125f;
      float mx = fmaxf(fmaxf(v0, v1), fmaxf(v2, v3));
      mx = fmaxf(mx, __shfl_xor(mx, 1));
      mx = fmaxf(mx, __shfl_xor(mx, 2));
      mx = fmaxf(mx, __shfl_xor(mx, 4));
      mx = fmaxf(mx, __shfl_xor(mx, 8));
      const float mn = fmaxf(m_[r], mx);
      const float al = __expf(m_[r] - mn);
      const float p0 = __expf(v0 - mn), p1 = __expf(v1 - mn);
      const float p2 = __expf(v2 - mn), p3 = __expf(v3 - mn);
      float rs = p0 + p1 + p2 + p3;
      rs += __shfl_xor(rs, 1); rs += __shfl_xor(rs, 2);
      rs += __shfl_xor(rs, 4); rs += __shfl_xor(rs, 8);
      l_[r] = l_[r] * al + rs;
      m_[r] = mn;
      #pragma unroll
      for (int dt = 0; dt < 4; ++dt) po[dt][r] *= al;
      const int q = 4 * g + r;
      const int key = (q & 7) << 4;
      ushort_t* pb = &Ps[w][0];
      ((ushort_t*)((char*)pb + q * 128 + ((2 * i) ^ key)))[0]       = f2bf(p0);
      ((ushort_t*)((char*)pb + q * 128 + ((32 + 2 * i) ^ key)))[0]  = f2bf(p1);
      ((ushort_t*)((char*)pb + q * 128 + ((64 + 2 * i) ^ key)))[0]  = f2bf(p2);
      ((ushort_t*)((char*)pb + q * 128 + ((96 + 2 * i) ^ key)))[0]  = f2bf(p3);
    }

    // ---- PV on Vs[cur] ----
    #pragma unroll
    for (int kc = 0; kc < 2; ++kc) {
      const int pbyte = i * 128 + ((kc * 64 + g * 16) ^ ((i & 7) << 4));
      const s16x8 pf = *(const s16x8*)((const char*)&Ps[w][0] + pbyte);
      #pragma unroll
      for (int dt = 0; dt < 4; ++dt) {
        const int vrow = dt * 16 + i;
        const int vbyte = vrow * 128 + ((kc * 64 + g * 16) ^ ((vrow & 7) << 4));
        const s16x8 vf = *(const s16x8*)((const char*)Vs[cur] + vbyte);
        po[dt] = __builtin_amdgcn_mfma_f32_16x16x32_bf16(pf, vf, po[dt], 0, 0, 0);
      }
    }

    __syncthreads();   // drains prefetch (flew during compute) + publishes buf
    cur ^= 1;
  }

  #pragma unroll
  for (int r = 0; r < 4; ++r) {
    const float inv = 1.0f / l_[r];
    const size_t row = (size_t)(b * SEQ + qt * 64 + w * 16 + 4 * g + r);
    #pragma unroll
    for (int dt = 0; dt < 4; ++dt)
      out[row * 512 + h * 64 + dt * 16 + i] = f2bf(po[dt][r] * inv);
  }
}

// ---------------------------------------------------------------------------
// Grouped conv1d (K=31) + bias + BN + SiLU. bf16 in/out, fp32 internal.
// lane = channel; sliding-window tap loop (round-9 verified).
// ---------------------------------------------------------------------------
__global__ __launch_bounds__(256) void dwconv_kernel(
    const ushort_t* __restrict__ in, const float* __restrict__ w,
    const float* __restrict__ dwb, const float* __restrict__ bng,
    const float* __restrict__ bnb, const float* __restrict__ bnm,
    const float* __restrict__ bnv, ushort_t* __restrict__ out)
{
  __shared__ __align__(16) float tile[94][64];
  const int s0 = blockIdx.x << 6;
  const int c0 = blockIdx.y << 6;
  const int b  = blockIdx.z;
  const int t  = threadIdx.x;

  {
    const int cl4 = (t & 15) << 2;
    #pragma unroll
    for (int it = 0; it < 6; ++it) {
      const int rr = it * 16 + (t >> 4);
      if (rr < 94) {
        const int gs = s0 - 15 + rr;
        float4 fv = make_float4(0.f, 0.f, 0.f, 0.f);
        if (gs >= 0 && gs < SEQ) {
          ushort4 uv = *(const ushort4*)(in + (size_t)(b * SEQ + gs) * 1024 + c0 + cl4);
          fv = make_float4(bf2f(uv.x), bf2f(uv.y), bf2f(uv.z), bf2f(uv.w));
        }
        *(float4*)&tile[rr][cl4] = fv;
      }
    }
  }
  __syncthreads();

  const int c  = t & 63;
  const int sb = (t >> 6) << 4;
  const int gc = c0 + c;

  float acc[16] = {};
  const float* wc = w + (size_t)gc * 248;
  for (int ci = 0; ci < 8; ++ci) {
    const int cl = (c & 56) | ci;
    const float* wp = wc + ci * 31;
    float wt[31];
    #pragma unroll
    for (int a = 0; a < 46; ++a) {
      const float va = tile[sb + a][cl];
      if (a < 31) wt[a] = wp[a];
      #pragma unroll
      for (int j = 0; j < 16; ++j) {
        if (j <= a && a - j <= 30)
          acc[j] = fmaf(wt[a - j], va, acc[j]);
      }
    }
  }

  const float bias = dwb[gc];
  const float mean = bnm[gc];
  const float rstd = rsqrtf(bnv[gc] + 1e-5f);
  const float gg   = bng[gc];
  const float bb2  = bnb[gc];
  #pragma unroll
  for (int j = 0; j < 16; ++j) {
    const int s = s0 + sb + j;
    float y = acc[j] + bias;
    y = (y - mean) * rstd * gg + bb2;
    out[(size_t)(b * SEQ + s) * 1024 + gc] = f2bf(silu_f(y));
  }
}

// ---------------------------------------------------------------------------
extern "C" void kernel_launch(void* const* d_in, const int* in_sizes, int n_in,
                              void* d_out, int out_size, void* d_ws, size_t ws_size,
                              hipStream_t stream)
{
  (void)in_sizes; (void)n_in; (void)out_size; (void)ws_size;
  const float* x        = (const float*)d_in[0];
  const float* ff1_g    = (const float*)d_in[1];
  const float* ff1_b    = (const float*)d_in[2];
  const float* ff1_win  = (const float*)d_in[3];
  const float* ff1_bin  = (const float*)d_in[4];
  const float* ff1_wout = (const float*)d_in[5];
  const float* ff1_bout = (const float*)d_in[6];
  const float* attn_g   = (const float*)d_in[7];
  const float* attn_b   = (const float*)d_in[8];
  const float* wqkv     = (const float*)d_in[9];
  const float* bqkv     = (const float*)d_in[10];
  const float* wo       = (const float*)d_in[11];
  const float* bo       = (const float*)d_in[12];
  const float* conv_g   = (const float*)d_in[13];
  const float* conv_b   = (const float*)d_in[14];
  const float* pw1_w    = (const float*)d_in[15];
  const float* pw1_b    = (const float*)d_in[16];
  const float* dw_w     = (const float*)d_in[17];
  const float* dw_b     = (const float*)d_in[18];
  const float* bn_g     = (const float*)d_in[19];
  const float* bn_b     = (const float*)d_in[20];
  const float* bn_m     = (const float*)d_in[21];
  const float* bn_v     = (const float*)d_in[22];
  const float* pw2_w    = (const float*)d_in[23];
  const float* pw2_b    = (const float*)d_in[24];
  const float* ff2_g    = (const float*)d_in[25];
  const float* ff2_b    = (const float*)d_in[26];
  const float* ff2_win  = (const float*)d_in[27];
  const float* ff2_bin  = (const float*)d_in[28];
  const float* ff2_wout = (const float*)d_in[29];
  const float* ff2_bout = (const float*)d_in[30];
  const float* fn_g     = (const float*)d_in[31];
  const float* fn_b     = (const float*)d_in[32];

  // workspace layout (bytes)
  char* wsb = (char*)d_ws;
  float*    xc    = (float*)(wsb);                           // 16 MB fp32 residual
  ushort_t* qkvb  = (ushort_t*)(wsb + (size_t)(16 << 20));   // 24 MB bf16 qkv (Q,K)
  ushort_t* vtb   = (ushort_t*)(wsb + (size_t)(40 << 20));   //  8 MB bf16 V^T
  ushort_t* h_bf  = (ushort_t*)(wsb + (size_t)(48 << 20));   //  8 MB bf16 LN out
  ushort_t* g_bf  = (ushort_t*)(wsb + (size_t)(56 << 20));   // 32 MB bf16 GLU out
  ushort_t* tb_bf = (ushort_t*)(wsb + (size_t)(88 << 20));   //  8 MB bf16 attn out
  ushort_t* cv_bf = (ushort_t*)(wsb + (size_t)(96 << 20));   // 16 MB bf16 conv out
  ushort_t* wb    = (ushort_t*)(wsb + (size_t)(112 << 20));  // ~18 MB bf16 weights

  ushort_t* ff1win_b  = wb;
  ushort_t* ff1wout_b = ff1win_b + 4096 * 512;
  ushort_t* wqkv_b    = ff1wout_b + 512 * 2048;
  ushort_t* wo_b      = wqkv_b + 1536 * 512;
  ushort_t* pw1w_b    = wo_b + 512 * 512;
  ushort_t* pw2w_b    = pw1w_b + 2048 * 512;
  ushort_t* ff2win_b  = pw2w_b + 512 * 1024;
  ushort_t* ff2wout_b = ff2win_b + 4096 * 512;

  float* outp = (float*)d_out;
  const dim3 B256(256);

  // ---- fused weight casts (one launch) ----
  {
    CastArgs a;
    const float* srcs[8] = {ff1_win, ff1_wout, wqkv, wo, pw1_w, pw2_w, ff2_win, ff2_wout};
    ushort_t*    dsts[8] = {ff1win_b, ff1wout_b, wqkv_b, wo_b, pw1w_b, pw2w_b, ff2win_b, ff2wout_b};
    const int    ns[8]   = {4096*512, 512*2048, 1536*512, 512*512,
                            2048*512, 512*1024, 4096*512, 512*2048};
    int cum = 0;
    for (int i = 0; i < 8; ++i) {
      a.src[i] = srcs[i]; a.dst[i] = dsts[i]; a.cum8[i] = cum; cum += ns[i] / 8;
    }
    f2b_multi<<<dim3((cum + 255) / 256), B256, 0, stream>>>(a, cum);
  }

  // ---- FF1: xc = x + 0.5*ff(x) ----
  ln512_kernel<1><<<dim3(NTOK / 4), B256, 0, stream>>>(x, ff1_g, ff1_b, h_bf);
  gemm_glu_bf16<0><<<dim3(32, 64), B256, 0, stream>>>(h_bf, ff1win_b, ff1_bin, g_bf, 2048, 512);
  gemm_bf16<1><<<dim3(4, 64), B256, 0, stream>>>(g_bf, ff1wout_b, ff1_bout, xc, 512, 2048, x, 0.5f);

  // ---- Attention: xc += attn(xc) ----
  ln512_kernel<1><<<dim3(NTOK / 4), B256, 0, stream>>>(xc, attn_g, attn_b, h_bf);
  gemm_qkv_bf16<<<dim3(12, 64), B256, 0, stream>>>(h_bf, wqkv_b, bqkv, qkvb, vtb, 512);
  attn_mfma<<<dim3(64, 16), B256, 0, stream>>>(qkvb, vtb, tb_bf);
  gemm_bf16<1><<<dim3(4, 64), B256, 0, stream>>>(tb_bf, wo_b, bo, xc, 512, 512, xc, 1.0f);

  // ---- Conv module: xc += conv(xc) ----
  ln512_kernel<1><<<dim3(NTOK / 4), B256, 0, stream>>>(xc, conv_g, conv_b, h_bf);
  gemm_glu_bf16<1><<<dim3(16, 64), B256, 0, stream>>>(h_bf, pw1w_b, pw1_b, g_bf, 1024, 512);
  dwconv_kernel<<<dim3(16, 16, 8), B256, 0, stream>>>(g_bf, dw_w, dw_b, bn_g, bn_b, bn_m, bn_v, cv_bf);
  gemm_bf16<1><<<dim3(4, 64), B256, 0, stream>>>(cv_bf, pw2w_b, pw2_b, xc, 512, 1024, xc, 1.0f);

  // ---- FF2: xc += 0.5*ff(xc) ----
  ln512_kernel<1><<<dim3(NTOK / 4), B256, 0, stream>>>(xc, ff2_g, ff2_b, h_bf);
  gemm_glu_bf16<0><<<dim3(32, 64), B256, 0, stream>>>(h_bf, ff2win_b, ff2_bin, g_bf, 2048, 512);
  gemm_bf16<1><<<dim3(4, 64), B256, 0, stream>>>(g_bf, ff2wout_b, ff2_bout, xc, 512, 2048, xc, 0.5f);

  // ---- Final LN ----
  ln512_kernel<0><<<dim3(NTOK / 4), B256, 0, stream>>>(xc, fn_g, fn_b, outp);
}